// Round 6
// baseline (475.988 us; speedup 1.0000x reference)
//
#include <hip/hip_runtime.h>
#include <hip/hip_bf16.h>

// ---------------------------------------------------------------------------
// HebbianNetwork: logits + 3 coactivation matrices.
//   B=8192, D_IN=1024, H1=H2=2048, N_CLS=1000
// Forward: bf16 MFMA (16x16x32) 128x128 tile, BK=64, XOR-swizzled LDS.
// Coacts: int8 MFMA (16x16x64) 128x128 tile, BK=128, split-K, partial-store.
// R1: split-K coacts. R2: i8 coacts (exact 0/1 matmul). R3: BK doubled +
// global-side XOR swizzle -> 0 bank conflicts. R4: partial-store + reduce
// (no atomics). R5: binarized-transpose fused into gemm epilogues via LDS
// (drops 3 transpose kernels + their 33MB re-reads); coact z=8/4/8 (4 blk/CU).
// ---------------------------------------------------------------------------

typedef short v8s __attribute__((ext_vector_type(8)));
typedef float v4f __attribute__((ext_vector_type(4)));
typedef int v4i __attribute__((ext_vector_type(4)));

enum { MODE_RELU = 0, MODE_LOGITS = 1 };

__device__ __forceinline__ void async_cp16(const void* gsrc, void* ldst) {
  __builtin_amdgcn_global_load_lds(
      (const __attribute__((address_space(1))) void*)gsrc,
      (__attribute__((address_space(3))) void*)ldst, 16, 0, 0);
}

// ---------------- bf16 forward gemm (BK=64, swizzled) ---------------------
// C[M,N] = A[M,K] @ B[N,K]^T + bias, A,B bf16 row-major inner-K.
// MODE_RELU:   store bf16 relu(acc+bias) to Cout [M, ldc]
// MODE_LOGITS: store fp32 (acc+bias) to Cout [M, ldc] for col < n_store
// WT: also emit T[col][sample] = (acc+bias > 0) int8, T row stride 8192,
//     via LDS tile (stride 144: 16B-aligned rows, 2 lanes/bank = free).
template <int MODE, int WT>
__global__ __launch_bounds__(256) void gemm_nt(
    const __hip_bfloat16* __restrict__ A, const __hip_bfloat16* __restrict__ B,
    const float* __restrict__ bias, void* __restrict__ Cout,
    char* __restrict__ Tout, int M, int N, int K, int n_store, int ldc) {
  __shared__ char smem[32768];
  __hip_bfloat16* sA = (__hip_bfloat16*)smem;           // 16KB
  __hip_bfloat16* sB = (__hip_bfloat16*)(smem + 16384); // 16KB
  const int t = threadIdx.x;
  const int m0 = blockIdx.y * 128;
  const int n0 = blockIdx.x * 128;

  // staging: tile = 128 rows x 8 granules(16B); chunk c = j*256+t
  // LDS byte offset c*16 (lane-contiguous, required by global_load_lds);
  // global granule g = slot ^ (row&7)  [XOR swizzle -> conflict-free reads]
  const __hip_bfloat16* aG[4];
  const __hip_bfloat16* bG[4];
  char* lA[4];
  char* lB[4];
#pragma unroll
  for (int j = 0; j < 4; j++) {
    const int c = j * 256 + t;
    const int row = c >> 3;
    const int g = (c & 7) ^ (row & 7);
    aG[j] = A + (size_t)(m0 + row) * K + g * 8;
    bG[j] = B + (size_t)(n0 + row) * K + g * 8;
    lA[j] = (char*)sA + c * 16;
    lB[j] = (char*)sB + c * 16;
  }

  const int lane = t & 63;
  const int wave = t >> 6;
  const int wm = (wave & 1) * 64;
  const int wn = (wave >> 1) * 64;
  const int lrow = lane & 15;
  const int quad = lane >> 4;

  // reader: lane (lrow,quad) wants granule (quad + 4*kg) of row wm+lrow+16i;
  // stored at slot (quad+4*kg) ^ (lrow&7)
  const int g0 = quad ^ (lrow & 7);
  const __hip_bfloat16* pa0 = sA + (wm + lrow) * 64 + g0 * 8;
  const __hip_bfloat16* pa1 = sA + (wm + lrow) * 64 + (g0 ^ 4) * 8;
  const __hip_bfloat16* pb0 = sB + (wn + lrow) * 64 + g0 * 8;
  const __hip_bfloat16* pb1 = sB + (wn + lrow) * 64 + (g0 ^ 4) * 8;

  v4f acc[4][4] = {};

  for (int k0 = 0; k0 < K; k0 += 64) {
#pragma unroll
    for (int j = 0; j < 4; j++) {
      async_cp16(aG[j] + k0, lA[j]);
      async_cp16(bG[j] + k0, lB[j]);
    }
    __syncthreads();

    v8s a0[4], b0[4], a1[4], b1[4];
#pragma unroll
    for (int i = 0; i < 4; i++) {
      a0[i] = *(const v8s*)(pa0 + i * 16 * 64);
      b0[i] = *(const v8s*)(pb0 + i * 16 * 64);
    }
#pragma unroll
    for (int mi = 0; mi < 4; mi++)
#pragma unroll
      for (int ni = 0; ni < 4; ni++)
        acc[mi][ni] = __builtin_amdgcn_mfma_f32_16x16x32_bf16(
            a0[mi], b0[ni], acc[mi][ni], 0, 0, 0);
#pragma unroll
    for (int i = 0; i < 4; i++) {
      a1[i] = *(const v8s*)(pa1 + i * 16 * 64);
      b1[i] = *(const v8s*)(pb1 + i * 16 * 64);
    }
#pragma unroll
    for (int mi = 0; mi < 4; mi++)
#pragma unroll
      for (int ni = 0; ni < 4; ni++)
        acc[mi][ni] = __builtin_amdgcn_mfma_f32_16x16x32_bf16(
            a1[mi], b1[ni], acc[mi][ni], 0, 0, 0);
    __syncthreads();
  }

  // bias per ni (col = n0+wn+ni*16+lrow)
  float bvv[4];
#pragma unroll
  for (int ni = 0; ni < 4; ni++) {
    const int col = n0 + wn + ni * 16 + lrow;
    bvv[ni] = 0.f;
    if (MODE == MODE_RELU) bvv[ni] = bias[col];
    else if (col < n_store) bvv[ni] = bias[col];
  }

  // main epilogue: C/D layout col=lane&15, row=quad*4+reg
#pragma unroll
  for (int ni = 0; ni < 4; ni++) {
    const int col = n0 + wn + ni * 16 + lrow;
#pragma unroll
    for (int mi = 0; mi < 4; mi++) {
      const int rowb = m0 + wm + mi * 16 + quad * 4;
#pragma unroll
      for (int r = 0; r < 4; r++) {
        const int row = rowb + r;
        const float v = acc[mi][ni][r] + bvv[ni];
        if (MODE == MODE_RELU) {
          ((__hip_bfloat16*)Cout)[(size_t)row * ldc + col] =
              __float2bfloat16(v > 0.f ? v : 0.f);
        } else {
          if (col < n_store)
            ((float*)Cout)[(size_t)row * ldc + col] = v;
        }
      }
    }
  }

  // fused binarized transpose: T[n0+c][m0+r] = (acc+bias > 0)
  if (WT) {
    char* sT = smem;  // 128 x 144 = 18432B, reuses staging LDS (K-loop done)
#pragma unroll
    for (int ni = 0; ni < 4; ni++) {
      const int c = wn + ni * 16 + lrow;
#pragma unroll
      for (int mi = 0; mi < 4; mi++) {
        const int r = wm + mi * 16 + quad * 4;
        char4 bits;
        bits.x = (acc[mi][ni][0] + bvv[ni] > 0.f) ? 1 : 0;
        bits.y = (acc[mi][ni][1] + bvv[ni] > 0.f) ? 1 : 0;
        bits.z = (acc[mi][ni][2] + bvv[ni] > 0.f) ? 1 : 0;
        bits.w = (acc[mi][ni][3] + bvv[ni] > 0.f) ? 1 : 0;
        *(char4*)&sT[c * 144 + r] = bits;
      }
    }
    __syncthreads();
    // flush: thread t writes 64B of T row n0 + (t>>1)
    const int c2 = t >> 1;
    const int hf = (t & 1) * 64;
    char* dst = Tout + (size_t)(n0 + c2) * 8192 + m0 + hf;
    const char* src = sT + c2 * 144 + hf;
#pragma unroll
    for (int j = 0; j < 4; j++)
      *(int4*)(dst + j * 16) = *(const int4*)(src + j * 16);
  }
}

// ---------------- int8 coact gemm (BK=128, swizzled, partial-store) -------
// P_z[M, n_store] = A[M, kz..] @ B[N, kz..]^T for slice z = blockIdx.z.
// A,B int8 (0/1) row-major inner-K. Plain fp32 stores (no RMW); exact
// (i32 partials < 2^24).
__global__ __launch_bounds__(256) void gemm_nt_i8(
    const char* __restrict__ A, const char* __restrict__ B,
    float* __restrict__ P, int M, int N, int Kc, int n_store, size_t slice) {
  __shared__ char sA[128 * 128];  // 16KB, row = 128B = 8 granules(16B)
  __shared__ char sB[128 * 128];
  const int t = threadIdx.x;
  const int m0 = blockIdx.y * 128;
  const int n0 = blockIdx.x * 128;
  const int kbeg = blockIdx.z * Kc;
  const int kend = kbeg + Kc;
  const size_t K = (size_t)Kc * gridDim.z;  // full K (row stride, bytes)
  float* __restrict__ Pz = P + (size_t)blockIdx.z * slice;

  const char* aG[4];
  const char* bG[4];
  char* lA[4];
  char* lB[4];
#pragma unroll
  for (int j = 0; j < 4; j++) {
    const int c = j * 256 + t;
    const int row = c >> 3;
    const int g = (c & 7) ^ (row & 7);
    aG[j] = A + (size_t)(m0 + row) * K + g * 16;
    bG[j] = B + (size_t)(n0 + row) * K + g * 16;
    lA[j] = sA + c * 16;
    lB[j] = sB + c * 16;
  }

  const int lane = t & 63;
  const int wave = t >> 6;
  const int wm = (wave & 1) * 64;
  const int wn = (wave >> 1) * 64;
  const int lrow = lane & 15;
  const int quad = lane >> 4;

  const int g0 = quad ^ (lrow & 7);
  const char* pa0 = sA + (wm + lrow) * 128 + g0 * 16;
  const char* pa1 = sA + (wm + lrow) * 128 + (g0 ^ 4) * 16;
  const char* pb0 = sB + (wn + lrow) * 128 + g0 * 16;
  const char* pb1 = sB + (wn + lrow) * 128 + (g0 ^ 4) * 16;

  v4i acc[4][4] = {};

  for (int k0 = kbeg; k0 < kend; k0 += 128) {
#pragma unroll
    for (int j = 0; j < 4; j++) {
      async_cp16(aG[j] + k0, lA[j]);
      async_cp16(bG[j] + k0, lB[j]);
    }
    __syncthreads();

    v4i a0[4], b0[4], a1[4], b1[4];
#pragma unroll
    for (int i = 0; i < 4; i++) {
      a0[i] = *(const v4i*)(pa0 + i * 16 * 128);
      b0[i] = *(const v4i*)(pb0 + i * 16 * 128);
    }
#pragma unroll
    for (int mi = 0; mi < 4; mi++)
#pragma unroll
      for (int ni = 0; ni < 4; ni++)
        acc[mi][ni] = __builtin_amdgcn_mfma_i32_16x16x64_i8(
            a0[mi], b0[ni], acc[mi][ni], 0, 0, 0);
#pragma unroll
    for (int i = 0; i < 4; i++) {
      a1[i] = *(const v4i*)(pa1 + i * 16 * 128);
      b1[i] = *(const v4i*)(pb1 + i * 16 * 128);
    }
#pragma unroll
    for (int mi = 0; mi < 4; mi++)
#pragma unroll
      for (int ni = 0; ni < 4; ni++)
        acc[mi][ni] = __builtin_amdgcn_mfma_i32_16x16x64_i8(
            a1[mi], b1[ni], acc[mi][ni], 0, 0, 0);
    __syncthreads();
  }

  // epilogue: C/D layout col=lane&15, row=quad*4+reg; dense [M, n_store]
#pragma unroll
  for (int ni = 0; ni < 4; ni++) {
    const int col = n0 + wn + ni * 16 + lrow;
    if (col >= n_store) continue;
#pragma unroll
    for (int mi = 0; mi < 4; mi++) {
      const int rowb = m0 + wm + mi * 16 + quad * 4;
#pragma unroll
      for (int r = 0; r < 4; r++) {
        Pz[(size_t)(rowb + r) * n_store + col] = (float)acc[mi][ni][r];
      }
    }
  }
}

// out[i] = sum_z P[z*slice + i], float4-vectorized. slice in floats.
template <int Z>
__global__ __launch_bounds__(256) void reduce_part(
    const float* __restrict__ P, float* __restrict__ out, int n4, size_t slice) {
  const int i = blockIdx.x * 256 + threadIdx.x;
  if (i >= n4) return;
  float4 s = ((const float4*)P)[i];
#pragma unroll
  for (int z = 1; z < Z; z++) {
    const float4 v = ((const float4*)(P + (size_t)z * slice))[i];
    s.x += v.x; s.y += v.y; s.z += v.z; s.w += v.w;
  }
  ((float4*)out)[i] = s;
}

// ---------------------------------------------------------------------------
// out[c][r] = (in[r][c] > 0) ? 1 : 0 (int8). out is [Cpad=gridDim.x*64, R].
__global__ __launch_bounds__(256) void transpose_bin8f(
    const float* __restrict__ in, char* __restrict__ out,
    int R, int ldin, int Cphys) {
  __shared__ char tile[64][65];
  const int c0 = blockIdx.x * 64;
  const int r0 = blockIdx.y * 64;
  const int tx = threadIdx.x & 63;
  const int ty = threadIdx.x >> 6;  // 0..3
#pragma unroll
  for (int i = 0; i < 64; i += 4) {
    const int c = c0 + tx;
    const int r = r0 + ty + i;
    float v = 0.f;
    if (c < Cphys) v = in[(size_t)r * ldin + c];
    tile[ty + i][tx] = (v > 0.f) ? 1 : 0;
  }
  __syncthreads();
  const int u = threadIdx.x & 15;
  const int cg = threadIdx.x >> 4;
#pragma unroll
  for (int i = 0; i < 64; i += 16) {
    const int col = cg + i;
    char4 v;
    v.x = tile[4 * u + 0][col];
    v.y = tile[4 * u + 1][col];
    v.z = tile[4 * u + 2][col];
    v.w = tile[4 * u + 3][col];
    *(char4*)&out[(size_t)(c0 + col) * R + r0 + 4 * u] = v;
  }
}

// fused f32->bf16 for up to 4 arrays (fewer launches / tails)
struct Cvt4 {
  const float* src[4];
  __hip_bfloat16* dst[4];
  int n4[4];  // float4 counts
};
__global__ __launch_bounds__(256) void f32_to_bf16_multi(Cvt4 c) {
  int i = blockIdx.x * 256 + threadIdx.x;
#pragma unroll
  for (int s = 0; s < 4; s++) {
    if (i < c.n4[s]) {
      const float4 v = ((const float4*)c.src[s])[i];
      union { __hip_bfloat16 h[4]; ushort4 u; } cv;
      cv.h[0] = __float2bfloat16(v.x);
      cv.h[1] = __float2bfloat16(v.y);
      cv.h[2] = __float2bfloat16(v.z);
      cv.h[3] = __float2bfloat16(v.w);
      ((ushort4*)c.dst[s])[i] = cv.u;
      return;
    }
    i -= c.n4[s];
  }
}

// ---------------------------------------------------------------------------
extern "C" void kernel_launch(void* const* d_in, const int* in_sizes, int n_in,
                              void* d_out, int out_size, void* d_ws, size_t ws_size,
                              hipStream_t stream) {
  const float* x  = (const float*)d_in[0];
  const float* W1 = (const float*)d_in[1];
  const float* b1 = (const float*)d_in[2];
  const float* W2 = (const float*)d_in[3];
  const float* b2 = (const float*)d_in[4];
  const float* W3 = (const float*)d_in[5];
  const float* b3 = (const float*)d_in[6];

  float* logits = (float*)d_out;                        // [8192,1000]
  float* coact0 = logits + (size_t)8192 * 1000;         // [1024,2048]
  float* coact1 = coact0 + (size_t)1024 * 2048;         // [2048,2048]
  float* coact2 = coact1 + (size_t)2048 * 2048;         // [2048,1000]

  char* ws = (char*)d_ws;
  size_t off = 0;
  auto alloc = [&](size_t bytes) {
    char* p = ws + off;
    off += (bytes + 255) & ~(size_t)255;
    return p;
  };
  // Lifetimes: X,W1b die after gemm1; W2b after gemm2; W3b,A1 after gemm2/3;
  // A2 after gemm3. T2 aliases X; T3 aliases W2b; P aliases A1+A2 (64MiB).
  __hip_bfloat16* X   = (__hip_bfloat16*)alloc((size_t)8192 * 1024 * 2);  // 16MiB
  __hip_bfloat16* W1b = (__hip_bfloat16*)alloc((size_t)2048 * 1024 * 2);  //  4MiB
  __hip_bfloat16* W2b = (__hip_bfloat16*)alloc((size_t)2048 * 2048 * 2);  //  8MiB
  __hip_bfloat16* W3b = (__hip_bfloat16*)alloc((size_t)1024 * 2048 * 2);  //  4MiB (rows 1000..1023 garbage)
  __hip_bfloat16* A1  = (__hip_bfloat16*)alloc((size_t)8192 * 2048 * 2);  // 32MiB
  __hip_bfloat16* A2  = (__hip_bfloat16*)alloc((size_t)8192 * 2048 * 2);  // 32MiB
  char* T0 = (char*)alloc((size_t)1024 * 8192);  // Act0^T i8, 8MiB
  char* T1 = (char*)alloc((size_t)2048 * 8192);  // Act1^T i8, 16MiB
  char* T2 = (char*)X;    // Act2^T [2048,8192] i8, 16MiB (X dead after gemm1)
  char* T3 = (char*)W2b;  // Act3^T [1024,8192] i8,  8MiB (W2b dead after gemm2)
  float* P = (float*)A1;  // split-K partials, 64MiB (A1+A2 dead after gemm3)

  const dim3 blk(256);

  // dtype converts (fused)
  {
    Cvt4 c;
    c.src[0] = x;  c.dst[0] = X;   c.n4[0] = 8192 * 1024 / 4;
    c.src[1] = W1; c.dst[1] = W1b; c.n4[1] = 2048 * 1024 / 4;
    c.src[2] = W2; c.dst[2] = W2b; c.n4[2] = 2048 * 2048 / 4;
    c.src[3] = W3; c.dst[3] = W3b; c.n4[3] = 1000 * 2048 / 4;
    const int total = c.n4[0] + c.n4[1] + c.n4[2] + c.n4[3];
    f32_to_bf16_multi<<<(total + 255) / 256, blk, 0, stream>>>(c);
  }

  // Act0^T = (x>0)^T  [1024, 8192] i8
  transpose_bin8f<<<dim3(16, 128), blk, 0, stream>>>(x, T0, 8192, 1024, 1024);

  // z1 = X @ W1^T + b1; A1 = relu(z1) bf16; T1 = bits^T (fused)
  gemm_nt<MODE_RELU, 1><<<dim3(16, 64), blk, 0, stream>>>(
      X, W1b, b1, A1, T1, 8192, 2048, 1024, 2048, 2048);

  // z2 = A1 @ W2^T + b2; A2 = relu(z2) bf16; T2 = bits^T (fused)
  gemm_nt<MODE_RELU, 1><<<dim3(16, 64), blk, 0, stream>>>(
      A1, W2b, b2, A2, T2, 8192, 2048, 2048, 2048, 2048);

  // logits = A2 @ W3^T + b3 (store cols<1000); T3 = bits^T (fused; rows
  // 1000..1023 garbage, never read into stored coact2 cols)
  gemm_nt<MODE_LOGITS, 1><<<dim3(8, 64), blk, 0, stream>>>(
      A2, W3b, b3, logits, T3, 8192, 1024, 2048, 1000, 1000);

  // coact0 = Act0^T @ Act1 -> [1024,2048]; z=8 (Kc=1024), partials 8x8MiB
  gemm_nt_i8<<<dim3(16, 8, 8), blk, 0, stream>>>(T0, T1, P,
                                                 1024, 2048, 1024, 2048,
                                                 (size_t)1024 * 2048);
  reduce_part<8><<<1024 * 2048 / 4 / 256, blk, 0, stream>>>(
      P, coact0, 1024 * 2048 / 4, (size_t)1024 * 2048);

  // coact1 = Act1^T @ Act2 -> [2048,2048]; z=4 (Kc=2048), partials 4x16MiB
  gemm_nt_i8<<<dim3(16, 16, 4), blk, 0, stream>>>(T1, T2, P,
                                                  2048, 2048, 2048, 2048,
                                                  (size_t)2048 * 2048);
  reduce_part<4><<<2048 * 2048 / 4 / 256, blk, 0, stream>>>(
      P, coact1, 2048 * 2048 / 4, (size_t)2048 * 2048);

  // coact2 = Act2^T @ Act3 -> [2048,1000]; z=8 (Kc=1024), partials 8x~8MB
  gemm_nt_i8<<<dim3(8, 16, 8), blk, 0, stream>>>(T2, T3, P,
                                                 2048, 1024, 1024, 1000,
                                                 (size_t)2048 * 1000);
  reduce_part<8><<<2048 * 1000 / 4 / 256, blk, 0, stream>>>(
      P, coact2, 2048 * 1000 / 4, (size_t)2048 * 1000);
}

// Round 8
// 447.068 us; speedup vs baseline: 1.0647x; 1.0647x over previous
//
#include <hip/hip_runtime.h>
#include <hip/hip_bf16.h>

// ---------------------------------------------------------------------------
// HebbianNetwork: logits + 3 coactivation matrices.
//   B=8192, D_IN=1024, H1=H2=2048, N_CLS=1000
// Forward: bf16 MFMA (16x16x32) 128x128 tile, BK=64, XOR-swizzled LDS.
// Coacts: int8 MFMA (16x16x64) 128x128 tile, BK=128, split-K, partial-store.
// R1: split-K coacts. R2: i8 coacts (exact 0/1 matmul). R3: BK doubled +
// global-side XOR swizzle -> 0 bank conflicts. R4: partial-store + reduce.
// R5: binarized-transpose fused into gemm epilogues via LDS.
// R6 (regressed): z=8/4/8 doubled partial traffic for no occupancy gain.
// R7 (crashed; cause unclear — infra suspected). R8: exact R6 kernel code
// (known-passing) + launch-side-only revert to z=4/2/4 (coacts are
// L2-latency-bound, not occupancy-bound; halves partial traffic).
// ---------------------------------------------------------------------------

typedef short v8s __attribute__((ext_vector_type(8)));
typedef float v4f __attribute__((ext_vector_type(4)));
typedef int v4i __attribute__((ext_vector_type(4)));

enum { MODE_RELU = 0, MODE_LOGITS = 1 };

__device__ __forceinline__ void async_cp16(const void* gsrc, void* ldst) {
  __builtin_amdgcn_global_load_lds(
      (const __attribute__((address_space(1))) void*)gsrc,
      (__attribute__((address_space(3))) void*)ldst, 16, 0, 0);
}

// ---------------- bf16 forward gemm (BK=64, swizzled) ---------------------
// C[M,N] = A[M,K] @ B[N,K]^T + bias, A,B bf16 row-major inner-K.
// MODE_RELU:   store bf16 relu(acc+bias) to Cout [M, ldc]
// MODE_LOGITS: store fp32 (acc+bias) to Cout [M, ldc] for col < n_store
// WT: also emit T[col][sample] = (acc+bias > 0) int8, T row stride 8192,
//     via LDS tile (stride 144: 16B-aligned rows).
template <int MODE, int WT>
__global__ __launch_bounds__(256) void gemm_nt(
    const __hip_bfloat16* __restrict__ A, const __hip_bfloat16* __restrict__ B,
    const float* __restrict__ bias, void* __restrict__ Cout,
    char* __restrict__ Tout, int M, int N, int K, int n_store, int ldc) {
  __shared__ char smem[32768];
  __hip_bfloat16* sA = (__hip_bfloat16*)smem;           // 16KB
  __hip_bfloat16* sB = (__hip_bfloat16*)(smem + 16384); // 16KB
  const int t = threadIdx.x;
  const int m0 = blockIdx.y * 128;
  const int n0 = blockIdx.x * 128;

  // staging: tile = 128 rows x 8 granules(16B); chunk c = j*256+t
  // LDS byte offset c*16 (lane-contiguous, required by global_load_lds);
  // global granule g = slot ^ (row&7)  [XOR swizzle -> conflict-free reads]
  const __hip_bfloat16* aG[4];
  const __hip_bfloat16* bG[4];
  char* lA[4];
  char* lB[4];
#pragma unroll
  for (int j = 0; j < 4; j++) {
    const int c = j * 256 + t;
    const int row = c >> 3;
    const int g = (c & 7) ^ (row & 7);
    aG[j] = A + (size_t)(m0 + row) * K + g * 8;
    bG[j] = B + (size_t)(n0 + row) * K + g * 8;
    lA[j] = (char*)sA + c * 16;
    lB[j] = (char*)sB + c * 16;
  }

  const int lane = t & 63;
  const int wave = t >> 6;
  const int wm = (wave & 1) * 64;
  const int wn = (wave >> 1) * 64;
  const int lrow = lane & 15;
  const int quad = lane >> 4;

  // reader: lane (lrow,quad) wants granule (quad + 4*kg) of row wm+lrow+16i;
  // stored at slot (quad+4*kg) ^ (lrow&7)
  const int g0 = quad ^ (lrow & 7);
  const __hip_bfloat16* pa0 = sA + (wm + lrow) * 64 + g0 * 8;
  const __hip_bfloat16* pa1 = sA + (wm + lrow) * 64 + (g0 ^ 4) * 8;
  const __hip_bfloat16* pb0 = sB + (wn + lrow) * 64 + g0 * 8;
  const __hip_bfloat16* pb1 = sB + (wn + lrow) * 64 + (g0 ^ 4) * 8;

  v4f acc[4][4] = {};

  for (int k0 = 0; k0 < K; k0 += 64) {
#pragma unroll
    for (int j = 0; j < 4; j++) {
      async_cp16(aG[j] + k0, lA[j]);
      async_cp16(bG[j] + k0, lB[j]);
    }
    __syncthreads();

    v8s a0[4], b0[4], a1[4], b1[4];
#pragma unroll
    for (int i = 0; i < 4; i++) {
      a0[i] = *(const v8s*)(pa0 + i * 16 * 64);
      b0[i] = *(const v8s*)(pb0 + i * 16 * 64);
    }
#pragma unroll
    for (int mi = 0; mi < 4; mi++)
#pragma unroll
      for (int ni = 0; ni < 4; ni++)
        acc[mi][ni] = __builtin_amdgcn_mfma_f32_16x16x32_bf16(
            a0[mi], b0[ni], acc[mi][ni], 0, 0, 0);
#pragma unroll
    for (int i = 0; i < 4; i++) {
      a1[i] = *(const v8s*)(pa1 + i * 16 * 64);
      b1[i] = *(const v8s*)(pb1 + i * 16 * 64);
    }
#pragma unroll
    for (int mi = 0; mi < 4; mi++)
#pragma unroll
      for (int ni = 0; ni < 4; ni++)
        acc[mi][ni] = __builtin_amdgcn_mfma_f32_16x16x32_bf16(
            a1[mi], b1[ni], acc[mi][ni], 0, 0, 0);
    __syncthreads();
  }

  // bias per ni (col = n0+wn+ni*16+lrow)
  float bvv[4];
#pragma unroll
  for (int ni = 0; ni < 4; ni++) {
    const int col = n0 + wn + ni * 16 + lrow;
    bvv[ni] = 0.f;
    if (MODE == MODE_RELU) bvv[ni] = bias[col];
    else if (col < n_store) bvv[ni] = bias[col];
  }

  // main epilogue: C/D layout col=lane&15, row=quad*4+reg
#pragma unroll
  for (int ni = 0; ni < 4; ni++) {
    const int col = n0 + wn + ni * 16 + lrow;
#pragma unroll
    for (int mi = 0; mi < 4; mi++) {
      const int rowb = m0 + wm + mi * 16 + quad * 4;
#pragma unroll
      for (int r = 0; r < 4; r++) {
        const int row = rowb + r;
        const float v = acc[mi][ni][r] + bvv[ni];
        if (MODE == MODE_RELU) {
          ((__hip_bfloat16*)Cout)[(size_t)row * ldc + col] =
              __float2bfloat16(v > 0.f ? v : 0.f);
        } else {
          if (col < n_store)
            ((float*)Cout)[(size_t)row * ldc + col] = v;
        }
      }
    }
  }

  // fused binarized transpose: T[n0+c][m0+r] = (acc+bias > 0)
  if (WT) {
    char* sT = smem;  // 128 x 144 = 18432B, reuses staging LDS (K-loop done)
#pragma unroll
    for (int ni = 0; ni < 4; ni++) {
      const int c = wn + ni * 16 + lrow;
#pragma unroll
      for (int mi = 0; mi < 4; mi++) {
        const int r = wm + mi * 16 + quad * 4;
        char4 bits;
        bits.x = (acc[mi][ni][0] + bvv[ni] > 0.f) ? 1 : 0;
        bits.y = (acc[mi][ni][1] + bvv[ni] > 0.f) ? 1 : 0;
        bits.z = (acc[mi][ni][2] + bvv[ni] > 0.f) ? 1 : 0;
        bits.w = (acc[mi][ni][3] + bvv[ni] > 0.f) ? 1 : 0;
        *(char4*)&sT[c * 144 + r] = bits;
      }
    }
    __syncthreads();
    // flush: thread t writes 64B of T row n0 + (t>>1)
    const int c2 = t >> 1;
    const int hf = (t & 1) * 64;
    char* dst = Tout + (size_t)(n0 + c2) * 8192 + m0 + hf;
    const char* src = sT + c2 * 144 + hf;
#pragma unroll
    for (int j = 0; j < 4; j++)
      *(int4*)(dst + j * 16) = *(const int4*)(src + j * 16);
  }
}

// ---------------- int8 coact gemm (BK=128, swizzled, partial-store) -------
// P_z[M, n_store] = A[M, kz..] @ B[N, kz..]^T for slice z = blockIdx.z.
// A,B int8 (0/1) row-major inner-K. Plain fp32 stores (no RMW); exact
// (i32 partials < 2^24).
__global__ __launch_bounds__(256) void gemm_nt_i8(
    const char* __restrict__ A, const char* __restrict__ B,
    float* __restrict__ P, int M, int N, int Kc, int n_store, size_t slice) {
  __shared__ char sA[128 * 128];  // 16KB, row = 128B = 8 granules(16B)
  __shared__ char sB[128 * 128];
  const int t = threadIdx.x;
  const int m0 = blockIdx.y * 128;
  const int n0 = blockIdx.x * 128;
  const int kbeg = blockIdx.z * Kc;
  const int kend = kbeg + Kc;
  const size_t K = (size_t)Kc * gridDim.z;  // full K (row stride, bytes)
  float* __restrict__ Pz = P + (size_t)blockIdx.z * slice;

  const char* aG[4];
  const char* bG[4];
  char* lA[4];
  char* lB[4];
#pragma unroll
  for (int j = 0; j < 4; j++) {
    const int c = j * 256 + t;
    const int row = c >> 3;
    const int g = (c & 7) ^ (row & 7);
    aG[j] = A + (size_t)(m0 + row) * K + g * 16;
    bG[j] = B + (size_t)(n0 + row) * K + g * 16;
    lA[j] = sA + c * 16;
    lB[j] = sB + c * 16;
  }

  const int lane = t & 63;
  const int wave = t >> 6;
  const int wm = (wave & 1) * 64;
  const int wn = (wave >> 1) * 64;
  const int lrow = lane & 15;
  const int quad = lane >> 4;

  const int g0 = quad ^ (lrow & 7);
  const char* pa0 = sA + (wm + lrow) * 128 + g0 * 16;
  const char* pa1 = sA + (wm + lrow) * 128 + (g0 ^ 4) * 16;
  const char* pb0 = sB + (wn + lrow) * 128 + g0 * 16;
  const char* pb1 = sB + (wn + lrow) * 128 + (g0 ^ 4) * 16;

  v4i acc[4][4] = {};

  for (int k0 = kbeg; k0 < kend; k0 += 128) {
#pragma unroll
    for (int j = 0; j < 4; j++) {
      async_cp16(aG[j] + k0, lA[j]);
      async_cp16(bG[j] + k0, lB[j]);
    }
    __syncthreads();

    v4i a0[4], b0[4], a1[4], b1[4];
#pragma unroll
    for (int i = 0; i < 4; i++) {
      a0[i] = *(const v4i*)(pa0 + i * 16 * 128);
      b0[i] = *(const v4i*)(pb0 + i * 16 * 128);
    }
#pragma unroll
    for (int mi = 0; mi < 4; mi++)
#pragma unroll
      for (int ni = 0; ni < 4; ni++)
        acc[mi][ni] = __builtin_amdgcn_mfma_i32_16x16x64_i8(
            a0[mi], b0[ni], acc[mi][ni], 0, 0, 0);
#pragma unroll
    for (int i = 0; i < 4; i++) {
      a1[i] = *(const v4i*)(pa1 + i * 16 * 128);
      b1[i] = *(const v4i*)(pb1 + i * 16 * 128);
    }
#pragma unroll
    for (int mi = 0; mi < 4; mi++)
#pragma unroll
      for (int ni = 0; ni < 4; ni++)
        acc[mi][ni] = __builtin_amdgcn_mfma_i32_16x16x64_i8(
            a1[mi], b1[ni], acc[mi][ni], 0, 0, 0);
    __syncthreads();
  }

  // epilogue: C/D layout col=lane&15, row=quad*4+reg; dense [M, n_store]
#pragma unroll
  for (int ni = 0; ni < 4; ni++) {
    const int col = n0 + wn + ni * 16 + lrow;
    if (col >= n_store) continue;
#pragma unroll
    for (int mi = 0; mi < 4; mi++) {
      const int rowb = m0 + wm + mi * 16 + quad * 4;
#pragma unroll
      for (int r = 0; r < 4; r++) {
        Pz[(size_t)(rowb + r) * n_store + col] = (float)acc[mi][ni][r];
      }
    }
  }
}

// out[i] = sum_z P[z*slice + i], float4-vectorized. slice in floats.
template <int Z>
__global__ __launch_bounds__(256) void reduce_part(
    const float* __restrict__ P, float* __restrict__ out, int n4, size_t slice) {
  const int i = blockIdx.x * 256 + threadIdx.x;
  if (i >= n4) return;
  float4 s = ((const float4*)P)[i];
#pragma unroll
  for (int z = 1; z < Z; z++) {
    const float4 v = ((const float4*)(P + (size_t)z * slice))[i];
    s.x += v.x; s.y += v.y; s.z += v.z; s.w += v.w;
  }
  ((float4*)out)[i] = s;
}

// ---------------------------------------------------------------------------
// out[c][r] = (in[r][c] > 0) ? 1 : 0 (int8). out is [Cpad=gridDim.x*64, R].
__global__ __launch_bounds__(256) void transpose_bin8f(
    const float* __restrict__ in, char* __restrict__ out,
    int R, int ldin, int Cphys) {
  __shared__ char tile[64][65];
  const int c0 = blockIdx.x * 64;
  const int r0 = blockIdx.y * 64;
  const int tx = threadIdx.x & 63;
  const int ty = threadIdx.x >> 6;  // 0..3
#pragma unroll
  for (int i = 0; i < 64; i += 4) {
    const int c = c0 + tx;
    const int r = r0 + ty + i;
    float v = 0.f;
    if (c < Cphys) v = in[(size_t)r * ldin + c];
    tile[ty + i][tx] = (v > 0.f) ? 1 : 0;
  }
  __syncthreads();
  const int u = threadIdx.x & 15;
  const int cg = threadIdx.x >> 4;
#pragma unroll
  for (int i = 0; i < 64; i += 16) {
    const int col = cg + i;
    char4 v;
    v.x = tile[4 * u + 0][col];
    v.y = tile[4 * u + 1][col];
    v.z = tile[4 * u + 2][col];
    v.w = tile[4 * u + 3][col];
    *(char4*)&out[(size_t)(c0 + col) * R + r0 + 4 * u] = v;
  }
}

// fused f32->bf16 for up to 4 arrays (fewer launches / tails)
struct Cvt4 {
  const float* src[4];
  __hip_bfloat16* dst[4];
  int n4[4];  // float4 counts
};
__global__ __launch_bounds__(256) void f32_to_bf16_multi(Cvt4 c) {
  int i = blockIdx.x * 256 + threadIdx.x;
#pragma unroll
  for (int s = 0; s < 4; s++) {
    if (i < c.n4[s]) {
      const float4 v = ((const float4*)c.src[s])[i];
      union { __hip_bfloat16 h[4]; ushort4 u; } cv;
      cv.h[0] = __float2bfloat16(v.x);
      cv.h[1] = __float2bfloat16(v.y);
      cv.h[2] = __float2bfloat16(v.z);
      cv.h[3] = __float2bfloat16(v.w);
      ((ushort4*)c.dst[s])[i] = cv.u;
      return;
    }
    i -= c.n4[s];
  }
}

// ---------------------------------------------------------------------------
extern "C" void kernel_launch(void* const* d_in, const int* in_sizes, int n_in,
                              void* d_out, int out_size, void* d_ws, size_t ws_size,
                              hipStream_t stream) {
  const float* x  = (const float*)d_in[0];
  const float* W1 = (const float*)d_in[1];
  const float* b1 = (const float*)d_in[2];
  const float* W2 = (const float*)d_in[3];
  const float* b2 = (const float*)d_in[4];
  const float* W3 = (const float*)d_in[5];
  const float* b3 = (const float*)d_in[6];

  float* logits = (float*)d_out;                        // [8192,1000]
  float* coact0 = logits + (size_t)8192 * 1000;         // [1024,2048]
  float* coact1 = coact0 + (size_t)1024 * 2048;         // [2048,2048]
  float* coact2 = coact1 + (size_t)2048 * 2048;         // [2048,1000]

  char* ws = (char*)d_ws;
  size_t off = 0;
  auto alloc = [&](size_t bytes) {
    char* p = ws + off;
    off += (bytes + 255) & ~(size_t)255;
    return p;
  };
  // Lifetimes: X,W1b die after gemm1; W2b after gemm2; W3b,A1 after gemm2/3;
  // A2 after gemm3. T2 aliases X; T3 aliases W2b; P aliases A1 (32MiB max use:
  // coact0 4x8MiB, coact1 2x16MiB, coact2 4x7.8MiB).
  __hip_bfloat16* X   = (__hip_bfloat16*)alloc((size_t)8192 * 1024 * 2);  // 16MiB
  __hip_bfloat16* W1b = (__hip_bfloat16*)alloc((size_t)2048 * 1024 * 2);  //  4MiB
  __hip_bfloat16* W2b = (__hip_bfloat16*)alloc((size_t)2048 * 2048 * 2);  //  8MiB
  __hip_bfloat16* W3b = (__hip_bfloat16*)alloc((size_t)1024 * 2048 * 2);  //  4MiB (rows 1000..1023 garbage)
  __hip_bfloat16* A1  = (__hip_bfloat16*)alloc((size_t)8192 * 2048 * 2);  // 32MiB
  __hip_bfloat16* A2  = (__hip_bfloat16*)alloc((size_t)8192 * 2048 * 2);  // 32MiB
  char* T0 = (char*)alloc((size_t)1024 * 8192);  // Act0^T i8, 8MiB
  char* T1 = (char*)alloc((size_t)2048 * 8192);  // Act1^T i8, 16MiB
  char* T2 = (char*)X;    // Act2^T [2048,8192] i8, 16MiB (X dead after gemm1)
  char* T3 = (char*)W2b;  // Act3^T [1024,8192] i8,  8MiB (W2b dead after gemm2)
  float* P = (float*)A1;  // split-K partials (A1 dead after gemm2; coacts run
                          // after gemm3)

  const dim3 blk(256);

  // dtype converts (fused)
  {
    Cvt4 c;
    c.src[0] = x;  c.dst[0] = X;   c.n4[0] = 8192 * 1024 / 4;
    c.src[1] = W1; c.dst[1] = W1b; c.n4[1] = 2048 * 1024 / 4;
    c.src[2] = W2; c.dst[2] = W2b; c.n4[2] = 2048 * 2048 / 4;
    c.src[3] = W3; c.dst[3] = W3b; c.n4[3] = 1000 * 2048 / 4;
    const int total = c.n4[0] + c.n4[1] + c.n4[2] + c.n4[3];
    f32_to_bf16_multi<<<(total + 255) / 256, blk, 0, stream>>>(c);
  }

  // Act0^T = (x>0)^T  [1024, 8192] i8
  transpose_bin8f<<<dim3(16, 128), blk, 0, stream>>>(x, T0, 8192, 1024, 1024);

  // z1 = X @ W1^T + b1; A1 = relu(z1) bf16; T1 = bits^T (fused)
  gemm_nt<MODE_RELU, 1><<<dim3(16, 64), blk, 0, stream>>>(
      X, W1b, b1, A1, T1, 8192, 2048, 1024, 2048, 2048);

  // z2 = A1 @ W2^T + b2; A2 = relu(z2) bf16; T2 = bits^T (fused)
  gemm_nt<MODE_RELU, 1><<<dim3(16, 64), blk, 0, stream>>>(
      A1, W2b, b2, A2, T2, 8192, 2048, 2048, 2048, 2048);

  // logits = A2 @ W3^T + b3 (store cols<1000); T3 = bits^T (fused; rows
  // 1000..1023 garbage, never read into stored coact2 cols)
  gemm_nt<MODE_LOGITS, 1><<<dim3(8, 64), blk, 0, stream>>>(
      A2, W3b, b3, logits, T3, 8192, 1024, 2048, 1000, 1000);

  // coact0 = Act0^T @ Act1 -> [1024,2048]; z=4 (Kc=2048), partials 4x8MiB
  gemm_nt_i8<<<dim3(16, 8, 4), blk, 0, stream>>>(T0, T1, P,
                                                 1024, 2048, 2048, 2048,
                                                 (size_t)1024 * 2048);
  reduce_part<4><<<1024 * 2048 / 4 / 256, blk, 0, stream>>>(
      P, coact0, 1024 * 2048 / 4, (size_t)1024 * 2048);

  // coact1 = Act1^T @ Act2 -> [2048,2048]; z=2 (Kc=4096), partials 2x16MiB
  gemm_nt_i8<<<dim3(16, 16, 2), blk, 0, stream>>>(T1, T2, P,
                                                  2048, 2048, 4096, 2048,
                                                  (size_t)2048 * 2048);
  reduce_part<2><<<2048 * 2048 / 4 / 256, blk, 0, stream>>>(
      P, coact1, 2048 * 2048 / 4, (size_t)2048 * 2048);

  // coact2 = Act2^T @ Act3 -> [2048,1000]; z=4 (Kc=2048), partials 4x~7.8MiB
  gemm_nt_i8<<<dim3(8, 16, 4), blk, 0, stream>>>(T2, T3, P,
                                                 2048, 1024, 2048, 1000,
                                                 (size_t)2048 * 1000);
  reduce_part<4><<<2048 * 1000 / 4 / 256, blk, 0, stream>>>(
      P, coact2, 2048 * 1000 / 4, (size_t)2048 * 1000);
}